// Round 13
// baseline (583.612 us; speedup 1.0000x reference)
//
#include <hip/hip_runtime.h>
#include <hip/hip_bf16.h>

typedef __bf16 bf16t;
typedef bf16t bf16x4 __attribute__((ext_vector_type(4)));
typedef bf16t bf16x8 __attribute__((ext_vector_type(8)));
typedef float f32x4 __attribute__((ext_vector_type(4)));

#define BT 8192      // B*T rows
#define TT 1024      // T
#define DM 1024      // d_model
#define DFF 4096
#define QSCALE 0.18033688011112042f  // 0.125 * log2(e)

static __device__ __forceinline__ f32x4 mfma16(bf16x8 a, bf16x8 b, f32x4 c) {
  return __builtin_amdgcn_mfma_f32_16x16x32_bf16(a, b, c, 0, 0, 0);
}
static __device__ __forceinline__ f32x4 f4zero() {
  f32x4 z = {0.f, 0.f, 0.f, 0.f};
  return z;
}
static __device__ __forceinline__ f32x4 vmax4(f32x4 a, f32x4 b) {
  f32x4 r;
#pragma unroll
  for (int i = 0; i < 4; i++) r[i] = fmaxf(a[i], b[i]);
  return r;
}
// async global->LDS, 16 bytes per lane; lds dest = wave-uniform base + lane*16
static __device__ __forceinline__ void gld16(const bf16t* g, bf16t* l) {
  __builtin_amdgcn_global_load_lds((const __attribute__((address_space(1))) void*)g,
                                   (__attribute__((address_space(3))) void*)l, 16, 0, 0);
}
// K-layout permutation: within each 32-elem chunk, natural c=(half,g,e) ->
// stored p = g*8 + half*4 + e. Makes each MFMA fragment one 16B chunk.
// Preserves c&3 and maps 4-aligned groups contiguously.
static __device__ __forceinline__ int cperm(int c) {
  return (c & ~31) + (((c >> 2) & 3) << 3) + (((c >> 4) & 1) << 2) + (c & 3);
}

// ---------------- z -> act (bf16, PERMUTED) + zbf (bf16, natural) ----------------
__global__ __launch_bounds__(256) void cvtz_kernel(const float* __restrict__ in,
                                                   bf16t* __restrict__ outp,
                                                   bf16t* __restrict__ outn, long n) {
  long i = ((long)blockIdx.x * 256 + threadIdx.x) * 4;
  if (i >= n) return;
  f32x4 v = *(const f32x4*)&in[i];
  bf16x4 o = {(bf16t)v[0], (bf16t)v[1], (bf16t)v[2], (bf16t)v[3]};
  *(bf16x4*)&outn[i] = o;
  int lo = (int)(i & 1023);
  long p = (i - lo) + cperm(lo);  // 4-contiguous since i%4==0
  *(bf16x4*)&outp[p] = o;
}

// ---------------- transpose-convert: out[N][M] = (bf16) in[M][N], PERMUTED k-cols ----------------
__global__ __launch_bounds__(256) void tcvt_kernel(const float* __restrict__ in,
                                                   bf16t* __restrict__ out, int M, int N) {
  __shared__ float T[64][65];
  const int t = threadIdx.x;
  const int ty = t >> 6, tx = t & 63;
  const long n0 = (long)blockIdx.x * 64, m0 = (long)blockIdx.y * 64;
#pragma unroll
  for (int p = 0; p < 16; ++p) {
    int a = ty * 16 + p;
    T[a][tx] = in[(m0 + a) * N + n0 + tx];
  }
  __syncthreads();
#pragma unroll
  for (int p = 0; p < 16; ++p) {
    int r = ty * 16 + p;
    out[(n0 + r) * M + m0 + cperm(tx)] = (bf16t)T[tx][r];
  }
}

// ---------------- pack Wq/Wk/Wv [H][D][Dh] -> transposed [3072][1024] bf16, PERMUTED ----------------
__global__ __launch_bounds__(256) void pack_qkv_t_kernel(const float* __restrict__ Wq,
                                                         const float* __restrict__ Wk,
                                                         const float* __restrict__ Wv,
                                                         bf16t* __restrict__ WT) {
  __shared__ float T[64][65];
  const int bx = blockIdx.x;  // 0..47 : sel*16 + h
  const int sel = bx >> 4, h = bx & 15;
  const float* src = ((sel == 0) ? Wq : (sel == 1) ? Wk : Wv) + (long)h * 65536;  // [1024][64]
  const long nbase = (long)sel * 1024 + h * 64;
  const long m0 = (long)blockIdx.y * 64;  // d tile
  const int t = threadIdx.x;
  const int ty = t >> 6, tx = t & 63;
#pragma unroll
  for (int p = 0; p < 16; ++p) {
    int a = ty * 16 + p;
    T[a][tx] = src[(m0 + a) * 64 + tx];  // [d_local][kk]
  }
  __syncthreads();
#pragma unroll
  for (int p = 0; p < 16; ++p) {
    int r = ty * 16 + p;  // kk
    WT[(nbase + r) * 1024 + m0 + cperm(tx)] = (bf16t)T[tx][r];
  }
}

__global__ __launch_bounds__(256) void pack_bias_kernel(const float* __restrict__ bq,
                                                        const float* __restrict__ bk,
                                                        const float* __restrict__ bv,
                                                        float* __restrict__ bqkv) {
  int i = blockIdx.x * 256 + threadIdx.x;
  if (i >= 3072) return;
  int sel = i >> 10, c = i & 1023;
  bqkv[i] = ((sel == 0) ? bq : (sel == 1) ? bk : bv)[c];
}

// ======== 256x128 / 4-wave / BK=32 GEMM, cperm b128 frag reads (QKV, W1) ========
// R9's proven geometry (acc[8][4], (256,2) bound -> 2 blocks/CU) + R11's proven
// b128 single-instruction fragment reads. 32 MFMA + 12 ds_read_b128 per barrier.
// EPI 0 (QKV): Q cols scaled+perm -> Cout; K cols perm -> Cout; V cols -> vTout
//   ([bh][64 d][1024 t], t perm'd) fused (replaces the vtrans kernel).
// EPI 1 (W1): bf16 out PERMUTED, +bias, relu.
template <int EPI>
__global__ __launch_bounds__(256, 2) void gemmBig_kernel(
    const bf16t* __restrict__ A, const bf16t* __restrict__ Bt,
    const float* __restrict__ bias, bf16t* __restrict__ Cout,
    bf16t* __restrict__ vTout, int M, int N, int K) {
  __shared__ __align__(16) bf16t As[2 * 256 * 32];  // 32 KB
  __shared__ __align__(16) bf16t Bs[2 * 128 * 32];  // 16 KB
  const int tid = threadIdx.x;
  const int lane = tid & 63;
  const int wid = tid >> 6;          // 0..3
  const int wm = wid >> 1;           // 0..1 (M half)
  const int wn = wid & 1;            // 0..1 (N half)
  const int g = lane >> 4, lr = lane & 15;

  const int gy = M >> 8;             // 256-row tiles (32)
  const int nwg = gridDim.x;
  const int chunk = nwg >> 3;
  const int wg = blockIdx.x;
  const int lid = (wg & 7) * chunk + (wg >> 3);
  const int gsz = gy << 3;           // 8 cols * gy rows per group
  const int group = lid / gsz;
  const int rem = lid - group * gsz;
  const int rr = rem >> 3;
  const int cc = (group << 3) + (rem & 7);
  const long brow = (long)rr * 256;
  const long bcol = (long)cc * 128;

  f32x4 acc[8][4];
#pragma unroll
  for (int i = 0; i < 8; i++)
#pragma unroll
    for (int j = 0; j < 4; j++) acc[i][j] = f4zero();

  // staging: per 4KB call, thread t fills LDS row (t>>2), 16B chunk (t&3);
  // source chunk pre-swizzled by ^((t>>3)&3) = ^((row>>1)&3).
  const int srow = tid >> 2;                       // 0..63
  const int csrc = (tid & 3) ^ ((tid >> 3) & 3);
  const bf16t* gA = &A[(brow + srow) * (long)K + 8 * csrc];
  const bf16t* gB = &Bt[(bcol + srow) * (long)K + 8 * csrc];
  bf16t* lA = As + wid * 512;  // wave-uniform base within a call (16 rows)
  bf16t* lB = Bs + wid * 512;

  auto stage = [&](int buf, int k0) {
#pragma unroll
    for (int c = 0; c < 4; ++c)
      gld16(gA + k0 + (long)(c * 64) * K, lA + buf * 8192 + c * 2048);
#pragma unroll
    for (int c = 0; c < 2; ++c)
      gld16(gB + k0 + (long)(c * 64) * K, lB + buf * 4096 + c * 2048);
  };
  // fragment read: one b128 at permuted chunk g of row, de-swizzled
  auto ldfA = [&](int buf, int row) -> bf16x8 {
    return *(const bf16x8*)(As + buf * 8192 + row * 32 + ((((row >> 1) ^ g) & 3) << 3));
  };
  auto ldfB = [&](int buf, int row) -> bf16x8 {
    return *(const bf16x8*)(Bs + buf * 4096 + row * 32 + ((((row >> 1) ^ g) & 3) << 3));
  };

  const int nt = K >> 5;
  stage(0, 0);
  __syncthreads();

  for (int t = 0; t < nt; ++t) {
    const int buf = t & 1;
    if (t + 1 < nt) stage(buf ^ 1, (t + 1) << 5);

    bf16x8 a[8], b[4];
#pragma unroll
    for (int i = 0; i < 8; i++) a[i] = ldfA(buf, wm * 128 + i * 16 + lr);
#pragma unroll
    for (int j = 0; j < 4; j++) b[j] = ldfB(buf, wn * 64 + j * 16 + lr);
#pragma unroll
    for (int i = 0; i < 8; i++)
#pragma unroll
      for (int j = 0; j < 4; j++) acc[i][j] = mfma16(a[i], b[j], acc[i][j]);

    __syncthreads();  // next buf staged (vmcnt drained) + cur reads done
  }

#pragma unroll
  for (int j = 0; j < 4; j++) {
    int col = (int)bcol + wn * 64 + j * 16 + lr;
    float bval = bias ? bias[col] : 0.f;
#pragma unroll
    for (int i = 0; i < 8; i++) {
      long row0 = brow + wm * 128 + i * 16 + 4 * g;
      if (EPI == 0 && col >= 2048) {
        // V: fused transpose to vT[bh][d][t] (t cperm'd; row0%4==0 so the 4
        // consecutive t map to 4 consecutive stored positions)
        int h2 = (col - 2048) >> 6, d = col & 63;
        long bb = row0 >> 10;
        int t0 = (int)(row0 & 1023);
        long idx = ((((bb << 4) + h2) << 6) + d) * 1024 + cperm(t0);
        bf16x4 ov;
#pragma unroll
        for (int r2 = 0; r2 < 4; r2++) ov[r2] = (bf16t)(acc[i][j][r2] + bval);
        *(bf16x4*)&vTout[idx] = ov;
      } else {
#pragma unroll
        for (int r2 = 0; r2 < 4; r2++) {
          long row = row0 + r2;
          float v = acc[i][j][r2] + bval;
          if (EPI == 0) {
            float vv = (col < 1024) ? v * QSCALE : v;
            Cout[row * N + cperm(col)] = (bf16t)vv;
          } else {
            Cout[row * N + cperm(col)] = (bf16t)fmaxf(v, 0.f);
          }
        }
      }
    }
  }
}

// ---------------- GEMM 128x128, BK=32, 3-buf counted-vmcnt, b128 frag reads (WO, W2) ----------------
// EPI 2: bf16 out natural, +bias, +resid(bf16 natural).
template <int EPI>
__global__ __launch_bounds__(256) void gemm_kernel(
    const bf16t* __restrict__ A, const bf16t* __restrict__ Bt,
    const float* __restrict__ bias, const bf16t* __restrict__ resid,
    void* __restrict__ Cout, int M, int N, int K) {
  __shared__ __align__(16) bf16t As[3 * 128 * 32];
  __shared__ __align__(16) bf16t Bs[3 * 128 * 32];
  const int tid = threadIdx.x;
  const int lane = tid & 63;
  const int wid = tid >> 6;
  const int wr = wid >> 1, wc = wid & 1;
  const int g = lane >> 4, lr = lane & 15;

  const int gy = M >> 7;
  const int nwg = gridDim.x;
  const int chunk = nwg >> 3;
  const int wg = blockIdx.x;
  const int lid = (wg & 7) * chunk + (wg >> 3);
  const int gsz = gy << 3;  // 8 * gy
  const int group = lid / gsz;
  const int rem = lid - group * gsz;
  const int rr = rem >> 3;
  const int cc = (group << 3) + (rem & 7);
  const long brow = (long)rr * 128;
  const long bcol = (long)cc * 128;

  f32x4 acc[4][4];
#pragma unroll
  for (int i = 0; i < 4; i++)
#pragma unroll
    for (int j = 0; j < 4; j++) acc[i][j] = f4zero();

  const int srow = tid >> 2;                       // 0..63 row within round
  const int csrc = (tid & 3) ^ ((tid >> 3) & 3);   // pre-swizzled global 16B-chunk
  const bf16t* gA = &A[(brow + srow) * (long)K + 8 * csrc];
  const bf16t* gB = &Bt[(bcol + srow) * (long)K + 8 * csrc];
  bf16t* lA = As + wid * 512;  // wave-uniform base
  bf16t* lB = Bs + wid * 512;

  auto stage = [&](int buf, int k0) {
    gld16(gA + k0, lA + buf * 4096);
    gld16(gA + k0 + (long)64 * K, lA + buf * 4096 + 2048);
    gld16(gB + k0, lB + buf * 4096);
    gld16(gB + k0 + (long)64 * K, lB + buf * 4096 + 2048);
  };
  auto ldf = [&](const bf16t* buf, int row) -> bf16x8 {
    return *(const bf16x8*)(buf + row * 32 + ((((row >> 1) ^ g) & 3) << 3));
  };

  const int nt = K >> 5;
  stage(0, 0);
  stage(1, 32);
  asm volatile("s_waitcnt vmcnt(4)" ::: "memory");
  __builtin_amdgcn_s_barrier();
  __builtin_amdgcn_sched_barrier(0);

  for (int t = 0; t < nt; ++t) {
    const int k2 = (t + 2) << 5;
    const bool pf = (k2 < K);
    if (pf) stage((t + 2) % 3, k2);

    const bf16t* bufA = As + (t % 3) * 4096;
    const bf16t* bufB = Bs + (t % 3) * 4096;
    bf16x8 af[4], bfv[4];
#pragma unroll
    for (int i = 0; i < 4; i++) af[i] = ldf(bufA, wr * 64 + i * 16 + lr);
#pragma unroll
    for (int j = 0; j < 4; j++) bfv[j] = ldf(bufB, wc * 64 + j * 16 + lr);
#pragma unroll
    for (int i = 0; i < 4; i++)
#pragma unroll
      for (int j = 0; j < 4; j++) acc[i][j] = mfma16(af[i], bfv[j], acc[i][j]);

    if (t + 1 < nt) {
      if (pf)
        asm volatile("s_waitcnt vmcnt(4)" ::: "memory");
      else
        asm volatile("s_waitcnt vmcnt(0)" ::: "memory");
      __builtin_amdgcn_s_barrier();
      __builtin_amdgcn_sched_barrier(0);
    }
  }

#pragma unroll
  for (int j = 0; j < 4; j++) {
    int col = (int)bcol + wc * 64 + j * 16 + lr;
    float bval = bias ? bias[col] : 0.f;
#pragma unroll
    for (int i = 0; i < 4; i++) {
      long row0 = brow + wr * 64 + i * 16 + 4 * g;
#pragma unroll
      for (int r2 = 0; r2 < 4; r2++) {
        long row = row0 + r2;
        float v = acc[i][j][r2] + bval;
        ((bf16t*)Cout)[row * N + col] = (bf16t)(v + (float)resid[row * N + col]);
      }
    }
  }
}

// ---------------- flash attention, swapped-QK^T, base-2 softmax, defer-max ----------------
// qkv: Q (cols 0..1023, scaled+permuted), K (1024..2047, permuted).
// vT[bh][64 d][1024 t], t permuted within 32-chunks (written by QKV epilogue).
__global__ __launch_bounds__(256) void attn_kernel(const bf16t* __restrict__ qkv,
                                                   const bf16t* __restrict__ vT,
                                                   bf16t* __restrict__ o) {
  const int bh = blockIdx.x;  // 0..127
  const int b = bh >> 4, h = bh & 15;
  const int qt = blockIdx.y;  // 0..15
  const int tid = threadIdx.x;
  const int lane = tid & 63;
  const int w = tid >> 6;
  const int g = lane >> 4, lr = lane & 15;

  __shared__ __align__(16) bf16t Qs[2 * 64 * 32];
  __shared__ __align__(16) bf16t Ks[2][2 * 64 * 32];
  __shared__ __align__(16) bf16t Vs[2][2 * 64 * 32];

  const long rowbase = (long)b * TT;
  const long qrow0 = rowbase + (long)qt * 64;

  const int sq = tid >> 2;                               // 0..63
  const int sco = (((tid & 3) ^ ((tid >> 3) & 3))) * 8;  // swizzled source granule offset

  const bf16t* qsrc = &qkv[(qrow0 + sq) * 3072 + h * 64 + sco];
  const bf16t* ksrc = &qkv[(rowbase + sq) * 3072 + 1024 + h * 64 + sco];
  const bf16t* vsrc = &vT[((long)bh * 64 + sq) * 1024 + sco];
  const int wbase = w * 512;  // wave-uniform LDS dest base (elems)

  auto stageQ = [&]() {
    gld16(qsrc, Qs + wbase);
    gld16(qsrc + 32, Qs + 2048 + wbase);
  };
  auto stageK = [&](int buf, int kt) {
    const bf16t* s = ksrc + (long)kt * 64 * 3072;
    gld16(s, Ks[buf] + wbase);
    gld16(s + 32, Ks[buf] + 2048 + wbase);
  };
  auto stageV = [&](int buf, int kt) {
    const bf16t* s = vsrc + kt * 64;
    gld16(s, Vs[buf] + wbase);
    gld16(s + 32, Vs[buf] + 2048 + wbase);
  };
  auto ldf = [&](const bf16t* base, int hh, int row) -> bf16x8 {
    return *(const bf16x8*)(base + hh * 2048 + row * 32 + ((((row >> 1) ^ g) & 3) << 3));
  };

  stageQ();
  stageK(0, 0);
  stageV(0, 0);
  __syncthreads();  // vmcnt(0) drained: tile 0 + Q ready

  const int qr = w * 16 + lr;
  const bf16x8 qb_lo = ldf(Qs, 0, qr);
  const bf16x8 qb_hi = ldf(Qs, 1, qr);

  f32x4 acc_o[4];
#pragma unroll
  for (int j = 0; j < 4; j++) acc_o[j] = f4zero();
  float mrun = -1e30f, lrun = 0.f;  // base-2 stats for q = w*16 + lr

  int cur = 0;
  for (int kt = 0; kt < 16; ++kt) {
    if (kt < 15) {
      stageK(cur ^ 1, kt + 1);
      stageV(cur ^ 1, kt + 1);
    }

    // S^T = K * Q^T (pre-scaled via Q): s[jt] = S2[k=jt*16+4g+r][q=lr]
    f32x4 s[4];
#pragma unroll
    for (int jt = 0; jt < 4; jt++) {
      int krow = jt * 16 + lr;
      bf16x8 ka_lo = ldf(Ks[cur], 0, krow);
      bf16x8 ka_hi = ldf(Ks[cur], 1, krow);
      f32x4 t = f4zero();
      t = mfma16(ka_lo, qb_lo, t);
      t = mfma16(ka_hi, qb_hi, t);
      s[jt] = t;
    }

    f32x4 mv = vmax4(vmax4(s[0], s[1]), vmax4(s[2], s[3]));
    float tm = fmaxf(fmaxf(mv[0], mv[1]), fmaxf(mv[2], mv[3]));
    tm = fmaxf(tm, __shfl_xor(tm, 16, 64));
    tm = fmaxf(tm, __shfl_xor(tm, 32, 64));

    // defer-max (T13): base-2 threshold 11.5 ~ e^8
    if (__any(tm > mrun + 11.5f)) {
      float mnew = fmaxf(mrun, tm);
      float corr = __builtin_amdgcn_exp2f(mrun - mnew);
      mrun = mnew;
      lrun *= corr;
#pragma unroll
      for (int r = 0; r < 4; r++) {
        float cq = __shfl(corr, 20 * g + r, 64);
#pragma unroll
        for (int dt = 0; dt < 4; dt++) acc_o[dt][r] *= cq;
      }
    }

    f32x4 sv = f4zero();
#pragma unroll
    for (int jt = 0; jt < 4; jt++)
#pragma unroll
      for (int r = 0; r < 4; r++) {
        float pv = __builtin_amdgcn_exp2f(s[jt][r] - mrun);
        s[jt][r] = pv;
        sv[r] += pv;
      }
    float tsum = sv[0] + sv[1] + sv[2] + sv[3];
    tsum += __shfl_xor(tsum, 16, 64);
    tsum += __shfl_xor(tsum, 32, 64);
    lrun += tsum;

    bf16x8 pa0, pa1;
#pragma unroll
    for (int r = 0; r < 4; r++) {
      pa0[r] = (bf16t)s[0][r];
      pa0[r + 4] = (bf16t)s[1][r];
      pa1[r] = (bf16t)s[2][r];
      pa1[r + 4] = (bf16t)s[3][r];
    }

#pragma unroll
    for (int dt = 0; dt < 4; dt++) {
      int vrow = dt * 16 + lr;
      bf16x8 vb_lo = ldf(Vs[cur], 0, vrow);
      bf16x8 vb_hi = ldf(Vs[cur], 1, vrow);
      acc_o[dt] = mfma16(pa0, vb_lo, acc_o[dt]);
      acc_o[dt] = mfma16(pa1, vb_hi, acc_o[dt]);
    }

    __syncthreads();  // next tile staged + guards buffer reuse
    cur ^= 1;
  }

  float inv = 1.0f / lrun;
#pragma unroll
  for (int r = 0; r < 4; r++) {
    float iq = __shfl(inv, 20 * g + r, 64);
    long row = qrow0 + w * 16 + 4 * g + r;
#pragma unroll
    for (int dt = 0; dt < 4; dt++) {
      o[row * (long)DM + cperm(h * 64 + dt * 16 + lr)] = (bf16t)(acc_o[dt][r] * iq);
    }
  }
}

// ---------------- LayerNorm: x[row][1024] bf16 -> act (bf16 PERMUTED) / resid (bf16 natural)
//                  / f32 natural (d_out) ----------------
__global__ __launch_bounds__(256) void ln_kernel(const bf16t* __restrict__ x,
                                                 const float* __restrict__ gamma,
                                                 const float* __restrict__ beta,
                                                 bf16t* __restrict__ out_act,
                                                 bf16t* __restrict__ out_res,
                                                 float* __restrict__ out_f32) {
  const long row = blockIdx.x;
  const int tid = threadIdx.x;
  const int idx = tid * 4;
  bf16x4 xv = *(const bf16x4*)&x[row * DM + idx];
  float v[4];
#pragma unroll
  for (int c = 0; c < 4; c++) v[c] = (float)xv[c];
  float s = v[0] + v[1] + v[2] + v[3];
  float ss = v[0] * v[0] + v[1] * v[1] + v[2] * v[2] + v[3] * v[3];
#pragma unroll
  for (int m = 1; m < 64; m <<= 1) {
    s += __shfl_xor(s, m, 64);
    ss += __shfl_xor(ss, m, 64);
  }
  __shared__ float red[8];
  const int w = tid >> 6, lane = tid & 63;
  if (lane == 0) {
    red[w] = s;
    red[4 + w] = ss;
  }
  __syncthreads();
  s = red[0] + red[1] + red[2] + red[3];
  ss = red[4] + red[5] + red[6] + red[7];
  float mean = s * (1.f / DM);
  float var = ss * (1.f / DM) - mean * mean;
  float inv = rsqrtf(var + 1e-5f);
  f32x4 ga = *(const f32x4*)&gamma[idx];
  f32x4 be = *(const f32x4*)&beta[idx];
  float y[4];
#pragma unroll
  for (int c = 0; c < 4; c++) y[c] = (v[c] - mean) * inv * ga[c] + be[c];
  if (out_act) {
    bf16x4 ob = {(bf16t)y[0], (bf16t)y[1], (bf16t)y[2], (bf16t)y[3]};
    *(bf16x4*)&out_act[row * DM + cperm(idx)] = ob;  // 4-contig (idx%4==0)
  }
  if (out_res) {
    bf16x4 ob = {(bf16t)y[0], (bf16t)y[1], (bf16t)y[2], (bf16t)y[3]};
    *(bf16x4*)&out_res[row * DM + idx] = ob;
  }
  if (out_f32) {
    f32x4 of = {y[0], y[1], y[2], y[3]};
    *(f32x4*)&out_f32[row * DM + idx] = of;
  }
}

extern "C" void kernel_launch(void* const* d_in, const int* in_sizes, int n_in,
                              void* d_out, int out_size, void* d_ws, size_t ws_size,
                              hipStream_t stream) {
  const float* z = (const float*)d_in[0];
  const float* Wq = (const float*)d_in[1];
  const float* bq = (const float*)d_in[2];
  const float* Wk = (const float*)d_in[3];
  const float* bk = (const float*)d_in[4];
  const float* Wv = (const float*)d_in[5];
  const float* bv = (const float*)d_in[6];
  const float* Wo = (const float*)d_in[7];
  const float* bo = (const float*)d_in[8];
  const float* W1 = (const float*)d_in[9];
  const float* b1 = (const float*)d_in[10];
  const float* W2 = (const float*)d_in[11];
  const float* b2 = (const float*)d_in[12];
  const float* g1 = (const float*)d_in[13];
  const float* be1 = (const float*)d_in[14];
  const float* g2 = (const float*)d_in[15];
  const float* be2 = (const float*)d_in[16];

  char* p = (char*)d_ws;
  auto alloc = [&](size_t bytes) {
    char* r = p;
    p += (bytes + 255) & ~(size_t)255;
    return r;
  };
  bf16t* wqkvT = (bf16t*)alloc((size_t)3072 * 1024 * 2);  // [3072][1024] permuted
  float* bqkv = (float*)alloc((size_t)3072 * 4);
  bf16t* woT = (bf16t*)alloc((size_t)1024 * 1024 * 2);    // permuted
  bf16t* w1T = (bf16t*)alloc((size_t)4096 * 1024 * 2);    // permuted
  bf16t* w2T = (bf16t*)alloc((size_t)1024 * 4096 * 2);    // permuted
  bf16t* act = (bf16t*)alloc((size_t)BT * 1024 * 2);      // permuted (GEMM A)
  bf16t* zbf = (bf16t*)alloc((size_t)BT * 1024 * 2);      // natural (resid)
  bf16t* obuf = (bf16t*)alloc((size_t)BT * 1024 * 2);     // permuted (GEMM A)
  bf16t* big = (bf16t*)alloc((size_t)BT * 4096 * 2);  // qkv Q/K / ffn-h (permuted)
  bf16t* tbuf = (bf16t*)alloc((size_t)BT * 1024 * 2);     // natural (LN input)
  bf16t* residf = (bf16t*)alloc((size_t)BT * 1024 * 2);   // natural (resid)
  // vT aliases tbuf (disjoint lifetimes: QKV->attn vs WO->LN)
  bf16t* vT = (bf16t*)tbuf;  // [128][64][1024], t permuted

  pack_qkv_t_kernel<<<dim3(48, 16), dim3(256), 0, stream>>>(Wq, Wk, Wv, wqkvT);
  pack_bias_kernel<<<dim3(12), dim3(256), 0, stream>>>(bq, bk, bv, bqkv);
  tcvt_kernel<<<dim3(16, 16), dim3(256), 0, stream>>>(Wo, woT, 1024, 1024);
  tcvt_kernel<<<dim3(64, 16), dim3(256), 0, stream>>>(W1, w1T, 1024, 4096);
  tcvt_kernel<<<dim3(16, 64), dim3(256), 0, stream>>>(W2, w2T, 4096, 1024);
  cvtz_kernel<<<dim3(8192), dim3(256), 0, stream>>>(z, act, zbf, (long)BT * 1024);

  for (int iter = 0; iter < 2; ++iter) {
    // QKV projection: 256x128 tiles, grid = 32*24 = 768; V fused into vT
    gemmBig_kernel<0><<<dim3(768), dim3(256), 0, stream>>>(
        act, wqkvT, bqkv, big, vT, BT, 3072, 1024);
    // attention (reads Q/K from big, V from vT; writes obuf permuted)
    attn_kernel<<<dim3(128, 16), dim3(256), 0, stream>>>(big, vT, obuf);
    // O-projection + residual: 128^2, grid = 512 (bf16 out natural -> LN)
    const bf16t* rsrc = (iter == 0) ? zbf : residf;
    gemm_kernel<2><<<dim3(512), dim3(256), 0, stream>>>(
        obuf, woT, bo, rsrc, (void*)tbuf, BT, 1024, 1024);
    if (iter == 1) {
      ln_kernel<<<dim3(8192), dim3(256), 0, stream>>>(tbuf, g1, be1, (bf16t*)nullptr,
                                                      (bf16t*)nullptr, (float*)d_out);
      break;
    }
    ln_kernel<<<dim3(8192), dim3(256), 0, stream>>>(tbuf, g1, be1, act, residf,
                                                    (float*)nullptr);
    // FFN: W1 on 256x128 (grid 1024, permuted out), W2 on 128^2 (grid 512)
    gemmBig_kernel<1><<<dim3(1024), dim3(256), 0, stream>>>(
        act, w1T, b1, big, (bf16t*)nullptr, BT, 4096, 1024);
    gemm_kernel<2><<<dim3(512), dim3(256), 0, stream>>>(
        big, w2T, b2, residf, (void*)tbuf, BT, 1024, 4096);
    ln_kernel<<<dim3(8192), dim3(256), 0, stream>>>(tbuf, g2, be2, act, residf,
                                                    (float*)nullptr);
  }
}

// Round 14
// 563.697 us; speedup vs baseline: 1.0353x; 1.0353x over previous
//
#include <hip/hip_runtime.h>
#include <hip/hip_bf16.h>

typedef __bf16 bf16t;
typedef bf16t bf16x4 __attribute__((ext_vector_type(4)));
typedef bf16t bf16x8 __attribute__((ext_vector_type(8)));
typedef float f32x4 __attribute__((ext_vector_type(4)));

#define BT 8192      // B*T rows
#define TT 1024      // T
#define DM 1024      // d_model
#define DFF 4096
#define QSCALE 0.18033688011112042f  // 0.125 * log2(e)

static __device__ __forceinline__ f32x4 mfma16(bf16x8 a, bf16x8 b, f32x4 c) {
  return __builtin_amdgcn_mfma_f32_16x16x32_bf16(a, b, c, 0, 0, 0);
}
static __device__ __forceinline__ f32x4 f4zero() {
  f32x4 z = {0.f, 0.f, 0.f, 0.f};
  return z;
}
static __device__ __forceinline__ f32x4 vmax4(f32x4 a, f32x4 b) {
  f32x4 r;
#pragma unroll
  for (int i = 0; i < 4; i++) r[i] = fmaxf(a[i], b[i]);
  return r;
}
// async global->LDS, 16 bytes per lane; lds dest = wave-uniform base + lane*16
static __device__ __forceinline__ void gld16(const bf16t* g, bf16t* l) {
  __builtin_amdgcn_global_load_lds((const __attribute__((address_space(1))) void*)g,
                                   (__attribute__((address_space(3))) void*)l, 16, 0, 0);
}
// K-layout permutation: within each 32-elem chunk, natural c=(half,g,e) ->
// stored p = g*8 + half*4 + e. Makes each MFMA fragment one 16B chunk.
// Preserves c&3 and maps 4-aligned groups contiguously.
static __device__ __forceinline__ int cperm(int c) {
  return (c & ~31) + (((c >> 2) & 3) << 3) + (((c >> 4) & 1) << 2) + (c & 3);
}

// ---------------- z -> act (bf16, PERMUTED) + zbf (bf16, natural) ----------------
__global__ __launch_bounds__(256) void cvtz_kernel(const float* __restrict__ in,
                                                   bf16t* __restrict__ outp,
                                                   bf16t* __restrict__ outn, long n) {
  long i = ((long)blockIdx.x * 256 + threadIdx.x) * 4;
  if (i >= n) return;
  f32x4 v = *(const f32x4*)&in[i];
  bf16x4 o = {(bf16t)v[0], (bf16t)v[1], (bf16t)v[2], (bf16t)v[3]};
  *(bf16x4*)&outn[i] = o;
  int lo = (int)(i & 1023);
  long p = (i - lo) + cperm(lo);  // 4-contiguous since i%4==0
  *(bf16x4*)&outp[p] = o;
}

// ---------------- transpose-convert: out[N][M] = (bf16) in[M][N], PERMUTED k-cols ----------------
__global__ __launch_bounds__(256) void tcvt_kernel(const float* __restrict__ in,
                                                   bf16t* __restrict__ out, int M, int N) {
  __shared__ float T[64][65];
  const int t = threadIdx.x;
  const int ty = t >> 6, tx = t & 63;
  const long n0 = (long)blockIdx.x * 64, m0 = (long)blockIdx.y * 64;
#pragma unroll
  for (int p = 0; p < 16; ++p) {
    int a = ty * 16 + p;
    T[a][tx] = in[(m0 + a) * N + n0 + tx];
  }
  __syncthreads();
#pragma unroll
  for (int p = 0; p < 16; ++p) {
    int r = ty * 16 + p;
    out[(n0 + r) * M + m0 + cperm(tx)] = (bf16t)T[tx][r];
  }
}

// ---------------- pack Wq/Wk/Wv [H][D][Dh] -> transposed [3072][1024] bf16, PERMUTED ----------------
__global__ __launch_bounds__(256) void pack_qkv_t_kernel(const float* __restrict__ Wq,
                                                         const float* __restrict__ Wk,
                                                         const float* __restrict__ Wv,
                                                         bf16t* __restrict__ WT) {
  __shared__ float T[64][65];
  const int bx = blockIdx.x;  // 0..47 : sel*16 + h
  const int sel = bx >> 4, h = bx & 15;
  const float* src = ((sel == 0) ? Wq : (sel == 1) ? Wk : Wv) + (long)h * 65536;  // [1024][64]
  const long nbase = (long)sel * 1024 + h * 64;
  const long m0 = (long)blockIdx.y * 64;  // d tile
  const int t = threadIdx.x;
  const int ty = t >> 6, tx = t & 63;
#pragma unroll
  for (int p = 0; p < 16; ++p) {
    int a = ty * 16 + p;
    T[a][tx] = src[(m0 + a) * 64 + tx];  // [d_local][kk]
  }
  __syncthreads();
#pragma unroll
  for (int p = 0; p < 16; ++p) {
    int r = ty * 16 + p;  // kk
    WT[(nbase + r) * 1024 + m0 + cperm(tx)] = (bf16t)T[tx][r];
  }
}

__global__ __launch_bounds__(256) void pack_bias_kernel(const float* __restrict__ bq,
                                                        const float* __restrict__ bk,
                                                        const float* __restrict__ bv,
                                                        float* __restrict__ bqkv) {
  int i = blockIdx.x * 256 + threadIdx.x;
  if (i >= 3072) return;
  int sel = i >> 10, c = i & 1023;
  bqkv[i] = ((sel == 0) ? bq : (sel == 1) ? bk : bv)[c];
}

// ---------------- GEMM 128x128, BK=32, 3-buf counted-vmcnt, b128 frag reads ----------------
// EPI 0 (QKV): Q cols scaled+perm -> Cout; K cols perm -> Cout; V cols (>=2048)
//   FUSED-transposed to vTout[bh][64 d][1024 t] (t perm'd) — replaces vtrans kernel.
// EPI 1 (W1): bf16 out PERMUTED, +bias, relu.
// EPI 2 (WO/W2): bf16 out natural, +bias, +resid(bf16 natural).
template <int EPI>
__global__ __launch_bounds__(256) void gemm_kernel(
    const bf16t* __restrict__ A, const bf16t* __restrict__ Bt,
    const float* __restrict__ bias, const bf16t* __restrict__ resid,
    void* __restrict__ Cout, bf16t* __restrict__ vTout, int M, int N, int K) {
  __shared__ __align__(16) bf16t As[3 * 128 * 32];
  __shared__ __align__(16) bf16t Bs[3 * 128 * 32];
  const int tid = threadIdx.x;
  const int lane = tid & 63;
  const int wid = tid >> 6;
  const int wr = wid >> 1, wc = wid & 1;
  const int g = lane >> 4, lr = lane & 15;

  const int gy = M >> 7;
  const int nwg = gridDim.x;
  const int chunk = nwg >> 3;
  const int wg = blockIdx.x;
  const int lid = (wg & 7) * chunk + (wg >> 3);
  const int gsz = gy << 3;  // 8 * gy
  const int group = lid / gsz;
  const int rem = lid - group * gsz;
  const int rr = rem >> 3;
  const int cc = (group << 3) + (rem & 7);
  const long brow = (long)rr * 128;
  const long bcol = (long)cc * 128;

  f32x4 acc[4][4];
#pragma unroll
  for (int i = 0; i < 4; i++)
#pragma unroll
    for (int j = 0; j < 4; j++) acc[i][j] = f4zero();

  const int srow = tid >> 2;                       // 0..63 row within round
  const int csrc = (tid & 3) ^ ((tid >> 3) & 3);   // pre-swizzled global 16B-chunk
  const bf16t* gA = &A[(brow + srow) * (long)K + 8 * csrc];
  const bf16t* gB = &Bt[(bcol + srow) * (long)K + 8 * csrc];
  bf16t* lA = As + wid * 512;  // wave-uniform base
  bf16t* lB = Bs + wid * 512;

  auto stage = [&](int buf, int k0) {
    gld16(gA + k0, lA + buf * 4096);
    gld16(gA + k0 + (long)64 * K, lA + buf * 4096 + 2048);
    gld16(gB + k0, lB + buf * 4096);
    gld16(gB + k0 + (long)64 * K, lB + buf * 4096 + 2048);
  };
  // fragment read: one b128 at permuted chunk g of row, de-swizzled
  auto ldf = [&](const bf16t* buf, int row) -> bf16x8 {
    return *(const bf16x8*)(buf + row * 32 + ((((row >> 1) ^ g) & 3) << 3));
  };

  const int nt = K >> 5;
  stage(0, 0);
  stage(1, 32);
  asm volatile("s_waitcnt vmcnt(4)" ::: "memory");
  __builtin_amdgcn_s_barrier();
  __builtin_amdgcn_sched_barrier(0);

  for (int t = 0; t < nt; ++t) {
    const int k2 = (t + 2) << 5;
    const bool pf = (k2 < K);
    if (pf) stage((t + 2) % 3, k2);

    const bf16t* bufA = As + (t % 3) * 4096;
    const bf16t* bufB = Bs + (t % 3) * 4096;
    bf16x8 af[4], bfv[4];
#pragma unroll
    for (int i = 0; i < 4; i++) af[i] = ldf(bufA, wr * 64 + i * 16 + lr);
#pragma unroll
    for (int j = 0; j < 4; j++) bfv[j] = ldf(bufB, wc * 64 + j * 16 + lr);
#pragma unroll
    for (int i = 0; i < 4; i++)
#pragma unroll
      for (int j = 0; j < 4; j++) acc[i][j] = mfma16(af[i], bfv[j], acc[i][j]);

    if (t + 1 < nt) {
      if (pf)
        asm volatile("s_waitcnt vmcnt(4)" ::: "memory");
      else
        asm volatile("s_waitcnt vmcnt(0)" ::: "memory");
      __builtin_amdgcn_s_barrier();
      __builtin_amdgcn_sched_barrier(0);
    }
  }

#pragma unroll
  for (int j = 0; j < 4; j++) {
    int col = (int)bcol + wc * 64 + j * 16 + lr;
    float bval = bias ? bias[col] : 0.f;
#pragma unroll
    for (int i = 0; i < 4; i++) {
      long row0 = brow + wr * 64 + i * 16 + 4 * g;
      if (EPI == 0 && col >= 2048) {
        // V: fused transpose to vT[bh][d][cperm(t)] (row0%4==0 -> 4 contiguous stored t)
        int h2 = (col - 2048) >> 6, d = col & 63;
        long bb = row0 >> 10;
        int t0 = (int)(row0 & 1023);
        long idx = ((((bb << 4) + h2) << 6) + d) * 1024 + cperm(t0);
        bf16x4 ov;
#pragma unroll
        for (int r2 = 0; r2 < 4; r2++) ov[r2] = (bf16t)(acc[i][j][r2] + bval);
        *(bf16x4*)&vTout[idx] = ov;
      } else {
#pragma unroll
        for (int r2 = 0; r2 < 4; r2++) {
          long row = row0 + r2;
          float v = acc[i][j][r2] + bval;
          if (EPI == 0) {
            float vv = (col < 1024) ? v * QSCALE : v;
            ((bf16t*)Cout)[row * N + cperm(col)] = (bf16t)vv;
          } else if (EPI == 1) {
            ((bf16t*)Cout)[row * N + cperm(col)] = (bf16t)fmaxf(v, 0.f);
          } else {
            ((bf16t*)Cout)[row * N + col] = (bf16t)(v + (float)resid[row * N + col]);
          }
        }
      }
    }
  }
}

// ---------------- flash attention, swapped-QK^T, base-2 softmax, defer-max ----------------
// qkv: Q (cols 0..1023, scaled+permuted), K (1024..2047, permuted).
// vT[bh][64 d][1024 t], t permuted within 32-chunks (written by QKV epilogue).
__global__ __launch_bounds__(256) void attn_kernel(const bf16t* __restrict__ qkv,
                                                   const bf16t* __restrict__ vT,
                                                   bf16t* __restrict__ o) {
  const int bh = blockIdx.x;  // 0..127
  const int b = bh >> 4, h = bh & 15;
  const int qt = blockIdx.y;  // 0..15
  const int tid = threadIdx.x;
  const int lane = tid & 63;
  const int w = tid >> 6;
  const int g = lane >> 4, lr = lane & 15;

  __shared__ __align__(16) bf16t Qs[2 * 64 * 32];
  __shared__ __align__(16) bf16t Ks[2][2 * 64 * 32];
  __shared__ __align__(16) bf16t Vs[2][2 * 64 * 32];

  const long rowbase = (long)b * TT;
  const long qrow0 = rowbase + (long)qt * 64;

  const int sq = tid >> 2;                               // 0..63
  const int sco = (((tid & 3) ^ ((tid >> 3) & 3))) * 8;  // swizzled source granule offset

  const bf16t* qsrc = &qkv[(qrow0 + sq) * 3072 + h * 64 + sco];
  const bf16t* ksrc = &qkv[(rowbase + sq) * 3072 + 1024 + h * 64 + sco];
  const bf16t* vsrc = &vT[((long)bh * 64 + sq) * 1024 + sco];
  const int wbase = w * 512;  // wave-uniform LDS dest base (elems)

  auto stageQ = [&]() {
    gld16(qsrc, Qs + wbase);
    gld16(qsrc + 32, Qs + 2048 + wbase);
  };
  auto stageK = [&](int buf, int kt) {
    const bf16t* s = ksrc + (long)kt * 64 * 3072;
    gld16(s, Ks[buf] + wbase);
    gld16(s + 32, Ks[buf] + 2048 + wbase);
  };
  auto stageV = [&](int buf, int kt) {
    const bf16t* s = vsrc + kt * 64;
    gld16(s, Vs[buf] + wbase);
    gld16(s + 32, Vs[buf] + 2048 + wbase);
  };
  auto ldf = [&](const bf16t* base, int hh, int row) -> bf16x8 {
    return *(const bf16x8*)(base + hh * 2048 + row * 32 + ((((row >> 1) ^ g) & 3) << 3));
  };

  stageQ();
  stageK(0, 0);
  stageV(0, 0);
  __syncthreads();  // vmcnt(0) drained: tile 0 + Q ready

  const int qr = w * 16 + lr;
  const bf16x8 qb_lo = ldf(Qs, 0, qr);
  const bf16x8 qb_hi = ldf(Qs, 1, qr);

  f32x4 acc_o[4];
#pragma unroll
  for (int j = 0; j < 4; j++) acc_o[j] = f4zero();
  float mrun = -1e30f, lrun = 0.f;  // base-2 stats for q = w*16 + lr

  int cur = 0;
  for (int kt = 0; kt < 16; ++kt) {
    if (kt < 15) {
      stageK(cur ^ 1, kt + 1);
      stageV(cur ^ 1, kt + 1);
    }

    // S^T = K * Q^T (pre-scaled via Q): s[jt] = S2[k=jt*16+4g+r][q=lr]
    f32x4 s[4];
#pragma unroll
    for (int jt = 0; jt < 4; jt++) {
      int krow = jt * 16 + lr;
      bf16x8 ka_lo = ldf(Ks[cur], 0, krow);
      bf16x8 ka_hi = ldf(Ks[cur], 1, krow);
      f32x4 t = f4zero();
      t = mfma16(ka_lo, qb_lo, t);
      t = mfma16(ka_hi, qb_hi, t);
      s[jt] = t;
    }

    f32x4 mv = vmax4(vmax4(s[0], s[1]), vmax4(s[2], s[3]));
    float tm = fmaxf(fmaxf(mv[0], mv[1]), fmaxf(mv[2], mv[3]));
    tm = fmaxf(tm, __shfl_xor(tm, 16, 64));
    tm = fmaxf(tm, __shfl_xor(tm, 32, 64));

    // defer-max (T13): base-2 threshold 11.5 ~ e^8
    if (__any(tm > mrun + 11.5f)) {
      float mnew = fmaxf(mrun, tm);
      float corr = __builtin_amdgcn_exp2f(mrun - mnew);
      mrun = mnew;
      lrun *= corr;
#pragma unroll
      for (int r = 0; r < 4; r++) {
        float cq = __shfl(corr, 20 * g + r, 64);
#pragma unroll
        for (int dt = 0; dt < 4; dt++) acc_o[dt][r] *= cq;
      }
    }

    f32x4 sv = f4zero();
#pragma unroll
    for (int jt = 0; jt < 4; jt++)
#pragma unroll
      for (int r = 0; r < 4; r++) {
        float pv = __builtin_amdgcn_exp2f(s[jt][r] - mrun);
        s[jt][r] = pv;
        sv[r] += pv;
      }
    float tsum = sv[0] + sv[1] + sv[2] + sv[3];
    tsum += __shfl_xor(tsum, 16, 64);
    tsum += __shfl_xor(tsum, 32, 64);
    lrun += tsum;

    bf16x8 pa0, pa1;
#pragma unroll
    for (int r = 0; r < 4; r++) {
      pa0[r] = (bf16t)s[0][r];
      pa0[r + 4] = (bf16t)s[1][r];
      pa1[r] = (bf16t)s[2][r];
      pa1[r + 4] = (bf16t)s[3][r];
    }

#pragma unroll
    for (int dt = 0; dt < 4; dt++) {
      int vrow = dt * 16 + lr;
      bf16x8 vb_lo = ldf(Vs[cur], 0, vrow);
      bf16x8 vb_hi = ldf(Vs[cur], 1, vrow);
      acc_o[dt] = mfma16(pa0, vb_lo, acc_o[dt]);
      acc_o[dt] = mfma16(pa1, vb_hi, acc_o[dt]);
    }

    __syncthreads();  // next tile staged + guards buffer reuse
    cur ^= 1;
  }

  float inv = 1.0f / lrun;
#pragma unroll
  for (int r = 0; r < 4; r++) {
    float iq = __shfl(inv, 20 * g + r, 64);
    long row = qrow0 + w * 16 + 4 * g + r;
#pragma unroll
    for (int dt = 0; dt < 4; dt++) {
      o[row * (long)DM + cperm(h * 64 + dt * 16 + lr)] = (bf16t)(acc_o[dt][r] * iq);
    }
  }
}

// ---------------- LayerNorm: x[row][1024] bf16 -> act (bf16 PERMUTED) / resid (bf16 natural)
//                  / f32 natural (d_out) ----------------
__global__ __launch_bounds__(256) void ln_kernel(const bf16t* __restrict__ x,
                                                 const float* __restrict__ gamma,
                                                 const float* __restrict__ beta,
                                                 bf16t* __restrict__ out_act,
                                                 bf16t* __restrict__ out_res,
                                                 float* __restrict__ out_f32) {
  const long row = blockIdx.x;
  const int tid = threadIdx.x;
  const int idx = tid * 4;
  bf16x4 xv = *(const bf16x4*)&x[row * DM + idx];
  float v[4];
#pragma unroll
  for (int c = 0; c < 4; c++) v[c] = (float)xv[c];
  float s = v[0] + v[1] + v[2] + v[3];
  float ss = v[0] * v[0] + v[1] * v[1] + v[2] * v[2] + v[3] * v[3];
#pragma unroll
  for (int m = 1; m < 64; m <<= 1) {
    s += __shfl_xor(s, m, 64);
    ss += __shfl_xor(ss, m, 64);
  }
  __shared__ float red[8];
  const int w = tid >> 6, lane = tid & 63;
  if (lane == 0) {
    red[w] = s;
    red[4 + w] = ss;
  }
  __syncthreads();
  s = red[0] + red[1] + red[2] + red[3];
  ss = red[4] + red[5] + red[6] + red[7];
  float mean = s * (1.f / DM);
  float var = ss * (1.f / DM) - mean * mean;
  float inv = rsqrtf(var + 1e-5f);
  f32x4 ga = *(const f32x4*)&gamma[idx];
  f32x4 be = *(const f32x4*)&beta[idx];
  float y[4];
#pragma unroll
  for (int c = 0; c < 4; c++) y[c] = (v[c] - mean) * inv * ga[c] + be[c];
  if (out_act) {
    bf16x4 ob = {(bf16t)y[0], (bf16t)y[1], (bf16t)y[2], (bf16t)y[3]};
    *(bf16x4*)&out_act[row * DM + cperm(idx)] = ob;  // 4-contig (idx%4==0)
  }
  if (out_res) {
    bf16x4 ob = {(bf16t)y[0], (bf16t)y[1], (bf16t)y[2], (bf16t)y[3]};
    *(bf16x4*)&out_res[row * DM + idx] = ob;
  }
  if (out_f32) {
    f32x4 of = {y[0], y[1], y[2], y[3]};
    *(f32x4*)&out_f32[row * DM + idx] = of;
  }
}

extern "C" void kernel_launch(void* const* d_in, const int* in_sizes, int n_in,
                              void* d_out, int out_size, void* d_ws, size_t ws_size,
                              hipStream_t stream) {
  const float* z = (const float*)d_in[0];
  const float* Wq = (const float*)d_in[1];
  const float* bq = (const float*)d_in[2];
  const float* Wk = (const float*)d_in[3];
  const float* bk = (const float*)d_in[4];
  const float* Wv = (const float*)d_in[5];
  const float* bv = (const float*)d_in[6];
  const float* Wo = (const float*)d_in[7];
  const float* bo = (const float*)d_in[8];
  const float* W1 = (const float*)d_in[9];
  const float* b1 = (const float*)d_in[10];
  const float* W2 = (const float*)d_in[11];
  const float* b2 = (const float*)d_in[12];
  const float* g1 = (const float*)d_in[13];
  const float* be1 = (const float*)d_in[14];
  const float* g2 = (const float*)d_in[15];
  const float* be2 = (const float*)d_in[16];

  char* p = (char*)d_ws;
  auto alloc = [&](size_t bytes) {
    char* r = p;
    p += (bytes + 255) & ~(size_t)255;
    return r;
  };
  bf16t* wqkvT = (bf16t*)alloc((size_t)3072 * 1024 * 2);  // [3072][1024] permuted
  float* bqkv = (float*)alloc((size_t)3072 * 4);
  bf16t* woT = (bf16t*)alloc((size_t)1024 * 1024 * 2);    // permuted
  bf16t* w1T = (bf16t*)alloc((size_t)4096 * 1024 * 2);    // permuted
  bf16t* w2T = (bf16t*)alloc((size_t)1024 * 4096 * 2);    // permuted
  bf16t* act = (bf16t*)alloc((size_t)BT * 1024 * 2);      // permuted (GEMM A)
  bf16t* zbf = (bf16t*)alloc((size_t)BT * 1024 * 2);      // natural (resid)
  bf16t* obuf = (bf16t*)alloc((size_t)BT * 1024 * 2);     // permuted (GEMM A)
  bf16t* big = (bf16t*)alloc((size_t)BT * 4096 * 2);  // qkv Q/K / ffn-h (permuted)
  bf16t* tbuf = (bf16t*)alloc((size_t)BT * 1024 * 2);     // natural (LN input)
  bf16t* residf = (bf16t*)alloc((size_t)BT * 1024 * 2);   // natural (resid)
  // vT aliases tbuf (disjoint lifetimes: QKV->attn vs WO->LN)
  bf16t* vT = (bf16t*)tbuf;  // [128][64][1024], t permuted

  pack_qkv_t_kernel<<<dim3(48, 16), dim3(256), 0, stream>>>(Wq, Wk, Wv, wqkvT);
  pack_bias_kernel<<<dim3(12), dim3(256), 0, stream>>>(bq, bk, bv, bqkv);
  tcvt_kernel<<<dim3(16, 16), dim3(256), 0, stream>>>(Wo, woT, 1024, 1024);
  tcvt_kernel<<<dim3(64, 16), dim3(256), 0, stream>>>(W1, w1T, 1024, 4096);
  tcvt_kernel<<<dim3(16, 64), dim3(256), 0, stream>>>(W2, w2T, 4096, 1024);
  cvtz_kernel<<<dim3(8192), dim3(256), 0, stream>>>(z, act, zbf, (long)BT * 1024);

  for (int iter = 0; iter < 2; ++iter) {
    // QKV projection: 128^2 grid = 24*64 = 1536; Q/K -> big (perm), V fused -> vT
    gemm_kernel<0><<<dim3(1536), dim3(256), 0, stream>>>(
        act, wqkvT, bqkv, (const bf16t*)nullptr, (void*)big, vT, BT, 3072, 1024);
    // attention (reads Q/K from big, V from vT; writes obuf permuted)
    attn_kernel<<<dim3(128, 16), dim3(256), 0, stream>>>(big, vT, obuf);
    // O-projection + residual: grid = 512 (bf16 out natural -> LN)
    const bf16t* rsrc = (iter == 0) ? zbf : residf;
    gemm_kernel<2><<<dim3(512), dim3(256), 0, stream>>>(
        obuf, woT, bo, rsrc, (void*)tbuf, (bf16t*)nullptr, BT, 1024, 1024);
    if (iter == 1) {
      ln_kernel<<<dim3(8192), dim3(256), 0, stream>>>(tbuf, g1, be1, (bf16t*)nullptr,
                                                      (bf16t*)nullptr, (float*)d_out);
      break;
    }
    ln_kernel<<<dim3(8192), dim3(256), 0, stream>>>(tbuf, g1, be1, act, residf,
                                                    (float*)nullptr);
    // FFN: W1 grid 2048 (permuted out), W2 grid 512 (natural out + resid)
    gemm_kernel<1><<<dim3(2048), dim3(256), 0, stream>>>(
        act, w1T, b1, (const bf16t*)nullptr, (void*)big, (bf16t*)nullptr, BT, 4096, 1024);
    gemm_kernel<2><<<dim3(512), dim3(256), 0, stream>>>(
        big, w2T, b2, residf, (void*)tbuf, (bf16t*)nullptr, BT, 1024, 4096);
    ln_kernel<<<dim3(8192), dim3(256), 0, stream>>>(tbuf, g2, be2, act, residf,
                                                    (float*)nullptr);
  }
}